// Round 3
// baseline (520.251 us; speedup 1.0000x reference)
//
#include <hip/hip_runtime.h>
#include <hip/hip_bf16.h>

#define B_ 2
#define S_ 1024
#define T_ 2048
#define H_ 3584
#define NH_ 28
#define NKV_ 4
#define HD_ 128
#define GROUPS_ 7
#define WINDOW_ 512
#define QKVD_ 4608
#define SCALE_ 0.08838834764831845f
#define PSTR_ 34
#define NCAST_ 256
#define THR_ 8.0f

typedef unsigned short u16;
typedef __bf16 bf16x8 __attribute__((ext_vector_type(8)));
typedef u16 u16x8 __attribute__((ext_vector_type(8)));
typedef float f32x4 __attribute__((ext_vector_type(4)));

__device__ inline u16 f2bf(float f) {
  union { float f; unsigned u; } v; v.f = f;
  unsigned r = v.u + 0x7fffu + ((v.u >> 16) & 1u);
  return (u16)(r >> 16);
}

__device__ __forceinline__ void g2l16(const void* g, void* l) {
  __builtin_amdgcn_global_load_lds(
      (const __attribute__((address_space(1))) unsigned int*)g,
      (__attribute__((address_space(3))) unsigned int*)l, 16, 0, 0);
}

// ---------------- fused dual cast f32 -> bf16 ----------------
__global__ void cast2_f32_to_bf16(const float4* __restrict__ a, ushort4* __restrict__ oa, int n4a,
                                  const float4* __restrict__ b, ushort4* __restrict__ ob, int n4b) {
  int i = blockIdx.x * blockDim.x + threadIdx.x;
  int stride = gridDim.x * blockDim.x;
  int tot = n4a + n4b;
  for (; i < tot; i += stride) {
    const float4* src; ushort4* dst; int j;
    if (i < n4a) { src = a; dst = oa; j = i; }
    else         { src = b; dst = ob; j = i - n4a; }
    float4 v = src[j];
    ushort4 o;
    o.x = f2bf(v.x); o.y = f2bf(v.y); o.z = f2bf(v.z); o.w = f2bf(v.w);
    dst[j] = o;
  }
}

// ---------------- GEMM: C = A * W^T (+bias), dbuf LDS + XCD swizzle ----------------
// 128x128 tile, BK=32, 4 waves; stage(t+1) overlaps compute(t); one barrier/K-step.
template<bool BIAS>
__global__ __launch_bounds__(256, 2) void gemm_bf16_nt(
    const u16* __restrict__ A,
    const u16* __restrict__ W,
    const float* __restrict__ bias,
    float* __restrict__ C,
    int M, int N, int K)
{
  __shared__ __align__(16) u16 As[2][128 * 32];
  __shared__ __align__(16) u16 Bs[2][128 * 32];
  int tiles_n = N >> 7;
  // bijective XCD swizzle (grid % 8 == 0 for both GEMMs)
  int bid = blockIdx.x;
  int cpx = gridDim.x >> 3;
  int swz = (bid & 7) * cpx + (bid >> 3);
  int tm = swz / tiles_n;
  int tn = swz % tiles_n;
  int m0 = tm << 7, n0 = tn << 7;
  int tid = threadIdx.x;
  int w = tid >> 6, lane = tid & 63;
  int lane16 = lane & 15, g = lane >> 4;
  int wm = (w >> 1) * 64, wn = (w & 1) * 64;

  int srow = tid >> 2, scb = (tid & 3) * 8;
  const u16* Ab = &A[(size_t)(m0 + srow) * K + scb];
  const u16* Wb = &W[(size_t)(n0 + srow) * K + scb];
  size_t rowK64 = (size_t)64 * K;

  f32x4 acc[4][4];
  #pragma unroll
  for (int i = 0; i < 4; i++)
    #pragma unroll
    for (int j = 0; j < 4; j++) acc[i][j] = (f32x4){0.f, 0.f, 0.f, 0.f};

  // prologue: stage tile 0 into buffer 0
  g2l16(Ab,          &As[0][tid * 8]);
  g2l16(Ab + rowK64, &As[0][2048 + tid * 8]);
  g2l16(Wb,          &Bs[0][tid * 8]);
  g2l16(Wb + rowK64, &Bs[0][2048 + tid * 8]);
  __syncthreads();

  int nt = K >> 5;
  for (int t = 0; t < nt; t++) {
    int cur = t & 1;
    if (t + 1 < nt) {   // issue next tile's loads early; latency hides under compute
      int k1 = (t + 1) << 5;
      g2l16(Ab + k1,          &As[cur ^ 1][tid * 8]);
      g2l16(Ab + rowK64 + k1, &As[cur ^ 1][2048 + tid * 8]);
      g2l16(Wb + k1,          &Bs[cur ^ 1][tid * 8]);
      g2l16(Wb + rowK64 + k1, &Bs[cur ^ 1][2048 + tid * 8]);
    }
    bf16x8 af[4], bfr[4];
    #pragma unroll
    for (int f = 0; f < 4; f++) {
      af[f]  = *reinterpret_cast<const bf16x8*>(&As[cur][(wm + f * 16 + lane16) * 32 + g * 8]);
      bfr[f] = *reinterpret_cast<const bf16x8*>(&Bs[cur][(wn + f * 16 + lane16) * 32 + g * 8]);
    }
    __builtin_amdgcn_s_setprio(1);
    #pragma unroll
    for (int i = 0; i < 4; i++)
      #pragma unroll
      for (int j = 0; j < 4; j++)
        acc[i][j] = __builtin_amdgcn_mfma_f32_16x16x32_bf16(af[i], bfr[j], acc[i][j], 0, 0, 0);
    __builtin_amdgcn_s_setprio(0);
    __syncthreads();   // compiler emits vmcnt(0) drain here -> next buffer ready
  }

  #pragma unroll
  for (int i = 0; i < 4; i++) {
    int row_b = m0 + wm + i * 16 + g * 4;
    #pragma unroll
    for (int j = 0; j < 4; j++) {
      int col = n0 + wn + j * 16 + lane16;
      float bv = BIAS ? bias[col] : 0.0f;
      #pragma unroll
      for (int r = 0; r < 4; r++) {
        C[(size_t)(row_b + r) * N + col] = acc[i][j][r] + bv;
      }
    }
  }
}

// ---------------- RoPE + split to Q*scale / K / V^T (bf16) ----------------
__global__ void rope_split_kernel(const float* __restrict__ qkv,
                                  const float* __restrict__ cosb,
                                  const float* __restrict__ sinb,
                                  u16* __restrict__ Q,
                                  u16* __restrict__ Kc,
                                  u16* __restrict__ Vt)
{
  int t = blockIdx.x;
  int hh = blockIdx.y * 4 + (threadIdx.x >> 6);
  int d = threadIdx.x & 63;
  int b = t / S_, s = t % S_;
  const float* row = qkv + (size_t)t * QKVD_ + hh * HD_;
  float x1 = row[d], x2 = row[d + 64];
  if (hh < NH_ + NKV_) {
    float c = cosb[t * 64 + d], sn = sinb[t * 64 + d];
    float o1 = x1 * c - x2 * sn;
    float o2 = x2 * c + x1 * sn;
    u16* dst;
    if (hh < NH_) {
      o1 *= SCALE_; o2 *= SCALE_;   // fold attention scale into Q
      dst = Q + ((size_t)(b * NH_ + hh) * S_ + s) * HD_;
    } else {
      dst = Kc + ((size_t)(b * NKV_ + (hh - NH_)) * S_ + s) * HD_;
    }
    dst[d] = f2bf(o1);
    dst[d + 64] = f2bf(o2);
  } else {
    int kvh = hh - NH_ - NKV_;
    u16* dst = Vt + ((size_t)(b * NKV_ + kvh) * HD_) * S_;
    dst[(size_t)d * S_ + s] = f2bf(x1);
    dst[(size_t)(d + 64) * S_ + s] = f2bf(x2);
  }
}

// ---------------- Flash attention + fused o_w cast ----------------
// blocks [0, NCAST_): grid-stride cast of o_w (overlaps with attn blocks).
// blocks [NCAST_, NCAST_+896): attn, 128 thr = 2 waves, wave owns 32 q rows.
__global__ __launch_bounds__(128, 2) void attn_kernel(
    const u16* __restrict__ Q,   // [B][NH][S][HD], pre-scaled
    const u16* __restrict__ Kc,  // [B][NKV][S][HD]
    const u16* __restrict__ Vt,  // [B][NKV][HD][S]
    u16* __restrict__ Oa,        // [T][NH*HD]
    const float4* __restrict__ cast_src,
    ushort4* __restrict__ cast_dst, int cast_n4)
{
  __shared__ __align__(16) u16 Plds[2 * 2 * 16 * PSTR_];
  int bid = blockIdx.x;
  if (bid < NCAST_) {
    int i = bid * 128 + threadIdx.x;
    for (; i < cast_n4; i += NCAST_ * 128) {
      float4 v = cast_src[i];
      ushort4 o;
      o.x = f2bf(v.x); o.y = f2bf(v.y); o.z = f2bf(v.z); o.w = f2bf(v.w);
      cast_dst[i] = o;
    }
    return;
  }
  int id = bid - NCAST_;
  int h = id % NH_;
  int rest = id / NH_;
  int qt = 15 - (rest & 15);   // heavy q-tiles dispatch first
  int b = rest >> 4;
  int w = threadIdx.x >> 6, lane = threadIdx.x & 63;
  int lane16 = lane & 15, g = lane >> 4;
  int kv = h / GROUPS_;

  const u16* Qh = Q + ((size_t)(b * NH_ + h) * S_) * HD_;
  const u16* Kh = Kc + ((size_t)(b * NKV_ + kv) * S_) * HD_;
  const u16* Vh = Vt + ((size_t)(b * NKV_ + kv) * HD_) * S_;

  int q0 = qt * 64 + w * 32;
  bf16x8 qf[2][4];
  #pragma unroll
  for (int rf = 0; rf < 2; rf++)
    #pragma unroll
    for (int c = 0; c < 4; c++)
      qf[rf][c] = *reinterpret_cast<const bf16x8*>(
          &Qh[(size_t)(q0 + rf * 16 + lane16) * HD_ + c * 32 + g * 8]);

  float m[2][4], l[2][4];
  #pragma unroll
  for (int rf = 0; rf < 2; rf++)
    #pragma unroll
    for (int r = 0; r < 4; r++) { m[rf][r] = -1e30f; l[rf][r] = 0.f; }
  f32x4 o[2][8];
  #pragma unroll
  for (int rf = 0; rf < 2; rf++)
    #pragma unroll
    for (int d = 0; d < 8; d++) o[rf][d] = (f32x4){0.f, 0.f, 0.f, 0.f};

  u16* Pw = &Plds[w * 2 * 16 * PSTR_];

  int k_start = qt * 64 - WINDOW_; if (k_start < 0) k_start = 0;
  int k_end = qt * 64 + 64;

  // prefetched K fragments for current tile
  bf16x8 kf[2][4];
  #pragma unroll
  for (int blk = 0; blk < 2; blk++)
    #pragma unroll
    for (int c = 0; c < 4; c++)
      kf[blk][c] = *reinterpret_cast<const bf16x8*>(
          &Kh[(size_t)(k_start + blk * 16 + lane16) * HD_ + c * 32 + g * 8]);

  for (int k0 = k_start; k0 < k_end; k0 += 32) {
    bool more = (k0 + 32 < k_end);
    // issue next tile's K loads early (hide under softmax+PV)
    bf16x8 kn[2][4];
    if (more) {
      #pragma unroll
      for (int blk = 0; blk < 2; blk++)
        #pragma unroll
        for (int c = 0; c < 4; c++)
          kn[blk][c] = *reinterpret_cast<const bf16x8*>(
              &Kh[(size_t)(k0 + 32 + blk * 16 + lane16) * HD_ + c * 32 + g * 8]);
    }
    // V fragments for current tile (hide under QK^T + softmax)
    bf16x8 vf[8];
    #pragma unroll
    for (int db = 0; db < 8; db++)
      vf[db] = *reinterpret_cast<const bf16x8*>(
          &Vh[(size_t)(db * 16 + lane16) * S_ + k0 + g * 8]);

    f32x4 s01[2][2];
    __builtin_amdgcn_s_setprio(1);
    #pragma unroll
    for (int rf = 0; rf < 2; rf++)
      #pragma unroll
      for (int blk = 0; blk < 2; blk++) {
        f32x4 sa = (f32x4){0.f, 0.f, 0.f, 0.f};
        #pragma unroll
        for (int c = 0; c < 4; c++)
          sa = __builtin_amdgcn_mfma_f32_16x16x32_bf16(qf[rf][c], kf[blk][c], sa, 0, 0, 0);
        s01[rf][blk] = sa;
      }
    __builtin_amdgcn_s_setprio(0);

    // masked scores + per-row tile max
    float sv0[2][4], sv1[2][4], am[2][4];
    bool cnd = true;
    #pragma unroll
    for (int rf = 0; rf < 2; rf++)
      #pragma unroll
      for (int r = 0; r < 4; r++) {
        int i = q0 + rf * 16 + g * 4 + r;
        int j0 = k0 + lane16;
        int j1 = j0 + 16;
        bool v0 = (j0 <= i) && (i - j0 <= WINDOW_);
        bool v1 = (j1 <= i) && (i - j1 <= WINDOW_);
        sv0[rf][r] = v0 ? s01[rf][0][r] : -1e30f;
        sv1[rf][r] = v1 ? s01[rf][1][r] : -1e30f;
        float a = fmaxf(sv0[rf][r], sv1[rf][r]);
        #pragma unroll
        for (int d = 8; d >= 1; d >>= 1) a = fmaxf(a, __shfl_xor(a, d));
        am[rf][r] = a;
        cnd = cnd && (a - m[rf][r] <= THR_);
      }

    if (__all(cnd)) {
      // defer-max: keep old m, no rescale (p bounded by e^THR)
      #pragma unroll
      for (int rf = 0; rf < 2; rf++)
        #pragma unroll
        for (int r = 0; r < 4; r++) {
          float mm = m[rf][r];
          float p0 = (sv0[rf][r] > -1e29f) ? __expf(sv0[rf][r] - mm) : 0.0f;
          float p1 = (sv1[rf][r] > -1e29f) ? __expf(sv1[rf][r] - mm) : 0.0f;
          float rs = p0 + p1;
          #pragma unroll
          for (int d = 8; d >= 1; d >>= 1) rs += __shfl_xor(rs, d);
          l[rf][r] += rs;
          Pw[(rf * 16 + g * 4 + r) * PSTR_ + lane16] = f2bf(p0);
          Pw[(rf * 16 + g * 4 + r) * PSTR_ + 16 + lane16] = f2bf(p1);
        }
    } else {
      #pragma unroll
      for (int rf = 0; rf < 2; rf++)
        #pragma unroll
        for (int r = 0; r < 4; r++) {
          float nm = fmaxf(m[rf][r], am[rf][r]);
          float p0 = (sv0[rf][r] > -1e29f) ? __expf(sv0[rf][r] - nm) : 0.0f;
          float p1 = (sv1[rf][r] > -1e29f) ? __expf(sv1[rf][r] - nm) : 0.0f;
          float rs = p0 + p1;
          #pragma unroll
          for (int d = 8; d >= 1; d >>= 1) rs += __shfl_xor(rs, d);
          float corr = __expf(m[rf][r] - nm);
          l[rf][r] = l[rf][r] * corr + rs;
          m[rf][r] = nm;
          #pragma unroll
          for (int db = 0; db < 8; db++) o[rf][db][r] *= corr;
          Pw[(rf * 16 + g * 4 + r) * PSTR_ + lane16] = f2bf(p0);
          Pw[(rf * 16 + g * 4 + r) * PSTR_ + 16 + lane16] = f2bf(p1);
        }
    }

    bf16x8 pa[2];
    #pragma unroll
    for (int rf = 0; rf < 2; rf++)
      pa[rf] = *reinterpret_cast<const bf16x8*>(&Pw[(rf * 16 + lane16) * PSTR_ + g * 8]);
    __builtin_amdgcn_s_setprio(1);
    #pragma unroll
    for (int rf = 0; rf < 2; rf++)
      #pragma unroll
      for (int db = 0; db < 8; db++)
        o[rf][db] = __builtin_amdgcn_mfma_f32_16x16x32_bf16(pa[rf], vf[db], o[rf][db], 0, 0, 0);
    __builtin_amdgcn_s_setprio(0);

    if (more) {
      #pragma unroll
      for (int blk = 0; blk < 2; blk++)
        #pragma unroll
        for (int c = 0; c < 4; c++)
          kf[blk][c] = kn[blk][c];
    }
  }

  #pragma unroll
  for (int rf = 0; rf < 2; rf++)
    #pragma unroll
    for (int db = 0; db < 8; db++) {
      #pragma unroll
      for (int r = 0; r < 4; r++) {
        int t = b * S_ + q0 + rf * 16 + g * 4 + r;
        int col = h * HD_ + db * 16 + lane16;
        Oa[(size_t)t * (NH_ * HD_) + col] = f2bf(o[rf][db][r] / l[rf][r]);
      }
    }
}

// ---------------- launch ----------------
extern "C" void kernel_launch(void* const* d_in, const int* in_sizes, int n_in,
                              void* d_out, int out_size, void* d_ws, size_t ws_size,
                              hipStream_t stream) {
  const float* hidden = (const float*)d_in[0];
  const float* cosb  = (const float*)d_in[1];
  const float* sinb  = (const float*)d_in[2];
  const float* qkv_w = (const float*)d_in[3];
  const float* qkv_b = (const float*)d_in[4];
  const float* o_w   = (const float*)d_in[5];
  float* out = (float*)d_out;

  char* ws = (char*)d_ws;
  u16*   hid_bf = (u16*)(ws);                      // 14,680,064 B
  u16*   w_bf   = (u16*)(ws + 14680064);           // 33,030,144 B (qkv_w, later o_w)
  float* qkvf   = (float*)(ws + 47710208);         // 37,748,736 B
  u16*   Qb     = (u16*)(ws + 85458944);           // 14,680,064 B
  u16*   Kb     = (u16*)(ws + 100139008);          //  2,097,152 B
  u16*   Vtb    = (u16*)(ws + 102236160);          //  2,097,152 B
  u16*   attn   = (u16*)(ws + 104333312);          // 14,680,064 B

  cast2_f32_to_bf16<<<2048, 256, 0, stream>>>(
      (const float4*)hidden, (ushort4*)hid_bf, 7340032 / 4,
      (const float4*)qkv_w, (ushort4*)w_bf, 16515072 / 4);

  gemm_bf16_nt<true><<<16 * 36, 256, 0, stream>>>(hid_bf, w_bf, qkv_b, qkvf, T_, QKVD_, H_);

  rope_split_kernel<<<dim3(T_, 9), 256, 0, stream>>>(qkvf, cosb, sinb, Qb, Kb, Vtb);

  // attn + fused o_w cast (cast blocks overlap latency-bound attn blocks)
  attn_kernel<<<NCAST_ + NH_ * 16 * B_, 128, 0, stream>>>(
      Qb, Kb, Vtb, attn,
      (const float4*)o_w, (ushort4*)w_bf, 12845056 / 4);

  gemm_bf16_nt<false><<<16 * 28, 256, 0, stream>>>(attn, w_bf, nullptr, out, T_, H_, H_);
}

// Round 4
// 403.740 us; speedup vs baseline: 1.2886x; 1.2886x over previous
//
#include <hip/hip_runtime.h>
#include <hip/hip_bf16.h>

#define B_ 2
#define S_ 1024
#define T_ 2048
#define H_ 3584
#define NH_ 28
#define NKV_ 4
#define HD_ 128
#define GROUPS_ 7
#define WINDOW_ 512
#define QKVD_ 4608
#define SCALE_ 0.08838834764831845f
#define PSTR_ 34
#define NCAST_ 256

typedef unsigned short u16;
typedef __bf16 bf16x8 __attribute__((ext_vector_type(8)));
typedef u16 u16x8 __attribute__((ext_vector_type(8)));
typedef float f32x4 __attribute__((ext_vector_type(4)));

__device__ inline u16 f2bf(float f) {
  union { float f; unsigned u; } v; v.f = f;
  unsigned r = v.u + 0x7fffu + ((v.u >> 16) & 1u);
  return (u16)(r >> 16);
}

__device__ __forceinline__ void g2l16(const void* g, void* l) {
  __builtin_amdgcn_global_load_lds(
      (const __attribute__((address_space(1))) unsigned int*)g,
      (__attribute__((address_space(3))) unsigned int*)l, 16, 0, 0);
}

// ---------------- fused dual cast f32 -> bf16 ----------------
__global__ void cast2_f32_to_bf16(const float4* __restrict__ a, ushort4* __restrict__ oa, int n4a,
                                  const float4* __restrict__ b, ushort4* __restrict__ ob, int n4b) {
  int i = blockIdx.x * blockDim.x + threadIdx.x;
  int stride = gridDim.x * blockDim.x;
  int tot = n4a + n4b;
  for (; i < tot; i += stride) {
    const float4* src; ushort4* dst; int j;
    if (i < n4a) { src = a; dst = oa; j = i; }
    else         { src = b; dst = ob; j = i - n4a; }
    float4 v = src[j];
    ushort4 o;
    o.x = f2bf(v.x); o.y = f2bf(v.y); o.z = f2bf(v.z); o.w = f2bf(v.w);
    dst[j] = o;
  }
}

// ---------------- GEMM (m97 structure + XCD swizzle): C = A * W^T (+bias) ----------------
// 128x128 tile, BK=32, 4 waves, global_load_lds w16, single-buffer 2-barrier.
template<bool BIAS>
__global__ __launch_bounds__(256, 2) void gemm_bf16_nt(
    const u16* __restrict__ A,
    const u16* __restrict__ W,
    const float* __restrict__ bias,
    float* __restrict__ C,
    int M, int N, int K)
{
  __shared__ __align__(16) u16 As[128 * 32];
  __shared__ __align__(16) u16 Bs[128 * 32];
  int tiles_n = N >> 7;
  // bijective XCD swizzle (grid % 8 == 0 for both GEMMs)
  int bid = blockIdx.x;
  int cpx = gridDim.x >> 3;
  int swz = (bid & 7) * cpx + (bid >> 3);
  int tm = swz / tiles_n;
  int tn = swz % tiles_n;
  int m0 = tm << 7, n0 = tn << 7;
  int tid = threadIdx.x;
  int w = tid >> 6, lane = tid & 63;
  int lane16 = lane & 15, g = lane >> 4;
  int wm = (w >> 1) * 64, wn = (w & 1) * 64;

  int srow = tid >> 2, scb = (tid & 3) * 8;
  const u16* Ab = &A[(size_t)(m0 + srow) * K + scb];
  const u16* Wb = &W[(size_t)(n0 + srow) * K + scb];
  size_t rowK64 = (size_t)64 * K;

  f32x4 acc[4][4];
  #pragma unroll
  for (int i = 0; i < 4; i++)
    #pragma unroll
    for (int j = 0; j < 4; j++) acc[i][j] = (f32x4){0.f, 0.f, 0.f, 0.f};

  for (int k0 = 0; k0 < K; k0 += 32) {
    __syncthreads();
    g2l16(Ab + k0,          &As[tid * 8]);
    g2l16(Ab + rowK64 + k0, &As[2048 + tid * 8]);
    g2l16(Wb + k0,          &Bs[tid * 8]);
    g2l16(Wb + rowK64 + k0, &Bs[2048 + tid * 8]);
    __syncthreads();
    bf16x8 af[4], bfr[4];
    #pragma unroll
    for (int f = 0; f < 4; f++) {
      af[f]  = *reinterpret_cast<const bf16x8*>(&As[(wm + f * 16 + lane16) * 32 + g * 8]);
      bfr[f] = *reinterpret_cast<const bf16x8*>(&Bs[(wn + f * 16 + lane16) * 32 + g * 8]);
    }
    __builtin_amdgcn_s_setprio(1);
    #pragma unroll
    for (int i = 0; i < 4; i++)
      #pragma unroll
      for (int j = 0; j < 4; j++)
        acc[i][j] = __builtin_amdgcn_mfma_f32_16x16x32_bf16(af[i], bfr[j], acc[i][j], 0, 0, 0);
    __builtin_amdgcn_s_setprio(0);
  }

  #pragma unroll
  for (int i = 0; i < 4; i++) {
    int row_b = m0 + wm + i * 16 + g * 4;
    #pragma unroll
    for (int j = 0; j < 4; j++) {
      int col = n0 + wn + j * 16 + lane16;
      float bv = BIAS ? bias[col] : 0.0f;
      #pragma unroll
      for (int r = 0; r < 4; r++) {
        C[(size_t)(row_b + r) * N + col] = acc[i][j][r] + bv;
      }
    }
  }
}

// ---------------- RoPE (Q*scale, K only — coalesced) ----------------
__global__ void rope_split_kernel(const float* __restrict__ qkv,
                                  const float* __restrict__ cosb,
                                  const float* __restrict__ sinb,
                                  u16* __restrict__ Q,
                                  u16* __restrict__ Kc)
{
  int t = blockIdx.x;
  int hh = blockIdx.y * 4 + (threadIdx.x >> 6);  // 0..31 (Q + K heads)
  int d = threadIdx.x & 63;
  int b = t / S_, s = t % S_;
  const float* row = qkv + (size_t)t * QKVD_ + hh * HD_;
  float x1 = row[d], x2 = row[d + 64];
  float c = cosb[t * 64 + d], sn = sinb[t * 64 + d];
  float o1 = x1 * c - x2 * sn;
  float o2 = x2 * c + x1 * sn;
  u16* dst;
  if (hh < NH_) {
    o1 *= SCALE_; o2 *= SCALE_;   // fold attention scale into Q
    dst = Q + ((size_t)(b * NH_ + hh) * S_ + s) * HD_;
  } else {
    dst = Kc + ((size_t)(b * NKV_ + (hh - NH_)) * S_ + s) * HD_;
  }
  dst[d] = f2bf(o1);
  dst[d + 64] = f2bf(o2);
}

// ---------------- V transpose via LDS (coalesced stores) ----------------
// grid (S/64, NKV, B), 128 threads. Vt[b][kv][d][s] <- qkv[t][(NH+NKV+kv)*HD + d]
__global__ void vtrans_kernel(const float* __restrict__ qkv, u16* __restrict__ Vt) {
  __shared__ float vs[64][129];
  int s0 = blockIdx.x * 64;
  int kv = blockIdx.y;
  int b = blockIdx.z;
  int tid = threadIdx.x;  // 0..127
  const float* src = qkv + (size_t)(b * S_ + s0) * QKVD_ + (size_t)(NH_ + NKV_ + kv) * HD_;
  #pragma unroll
  for (int i = 0; i < 16; i++) {
    int idx = tid + i * 128;          // 0..2047
    int s = idx >> 5, c4 = idx & 31;  // float4 col
    float4 v = *reinterpret_cast<const float4*>(&src[(size_t)s * QKVD_ + c4 * 4]);
    vs[s][c4 * 4 + 0] = v.x; vs[s][c4 * 4 + 1] = v.y;
    vs[s][c4 * 4 + 2] = v.z; vs[s][c4 * 4 + 3] = v.w;
  }
  __syncthreads();
  int d = tid;
  u16 tmp[64];
  #pragma unroll
  for (int s = 0; s < 64; s++) tmp[s] = f2bf(vs[s][d]);
  u16* dst = Vt + ((size_t)((b * NKV_ + kv) * HD_ + d)) * S_ + s0;
  #pragma unroll
  for (int i = 0; i < 8; i++)
    *reinterpret_cast<u16x8*>(&dst[i * 8]) = *reinterpret_cast<const u16x8*>(&tmp[i * 8]);
}

// ---------------- Flash attention + fused o_w cast, KV-slab XCD swizzle ----------------
// blocks [0, NCAST_): grid-stride cast of o_w.
// blocks [NCAST_, +896): attn; (bid-NCAST_)%8 = (b,kv) slab -> each XCD's L2
// holds exactly one 512KB K/V slab. 128 thr = 2 waves, wave owns 32 q rows.
__global__ __launch_bounds__(128, 2) void attn_kernel(
    const u16* __restrict__ Q,   // [B][NH][S][HD], pre-scaled
    const u16* __restrict__ Kc,  // [B][NKV][S][HD]
    const u16* __restrict__ Vt,  // [B][NKV][HD][S]
    u16* __restrict__ Oa,        // [T][NH*HD]
    const float4* __restrict__ cast_src,
    ushort4* __restrict__ cast_dst, int cast_n4)
{
  __shared__ __align__(16) u16 Plds[2 * 2 * 16 * PSTR_];
  int bid = blockIdx.x;
  if (bid < NCAST_) {
    int i = bid * 128 + threadIdx.x;
    for (; i < cast_n4; i += NCAST_ * 128) {
      float4 v = cast_src[i];
      ushort4 o;
      o.x = f2bf(v.x); o.y = f2bf(v.y); o.z = f2bf(v.z); o.w = f2bf(v.w);
      cast_dst[i] = o;
    }
    return;
  }
  int id = bid - NCAST_;          // NCAST_ % 8 == 0, so bid%8 == id%8 == slab
  int slab = id & 7;              // b*NKV + kv  -> XCD
  int b = slab >> 2, kv = slab & 3;
  int idx = id >> 3;              // 0..111
  int hg = idx % 7;
  int qt = 15 - idx / 7;          // heavy q-tiles dispatch first
  int h = kv * GROUPS_ + hg;
  int w = threadIdx.x >> 6, lane = threadIdx.x & 63;
  int lane16 = lane & 15, g = lane >> 4;

  const u16* Qh = Q + ((size_t)(b * NH_ + h) * S_) * HD_;
  const u16* Kh = Kc + ((size_t)(b * NKV_ + kv) * S_) * HD_;
  const u16* Vh = Vt + ((size_t)(b * NKV_ + kv) * HD_) * S_;

  int q0 = qt * 64 + w * 32;
  bf16x8 qf[2][4];
  #pragma unroll
  for (int rf = 0; rf < 2; rf++)
    #pragma unroll
    for (int c = 0; c < 4; c++)
      qf[rf][c] = *reinterpret_cast<const bf16x8*>(
          &Qh[(size_t)(q0 + rf * 16 + lane16) * HD_ + c * 32 + g * 8]);

  float m[2][4], l[2][4];
  #pragma unroll
  for (int rf = 0; rf < 2; rf++)
    #pragma unroll
    for (int r = 0; r < 4; r++) { m[rf][r] = -1e30f; l[rf][r] = 0.f; }
  f32x4 o[2][8];
  #pragma unroll
  for (int rf = 0; rf < 2; rf++)
    #pragma unroll
    for (int d = 0; d < 8; d++) o[rf][d] = (f32x4){0.f, 0.f, 0.f, 0.f};

  u16* Pw = &Plds[w * 2 * 16 * PSTR_];

  int k_start = qt * 64 - WINDOW_; if (k_start < 0) k_start = 0;
  int k_end = qt * 64 + 64;
  for (int k0 = k_start; k0 < k_end; k0 += 32) {
    // K fragments (shared by both row-frags)
    bf16x8 kf[2][4];
    #pragma unroll
    for (int blk = 0; blk < 2; blk++)
      #pragma unroll
      for (int c = 0; c < 4; c++)
        kf[blk][c] = *reinterpret_cast<const bf16x8*>(
            &Kh[(size_t)(k0 + blk * 16 + lane16) * HD_ + c * 32 + g * 8]);
    // V fragments issued early — latency hides under QK^T + softmax
    bf16x8 vf[8];
    #pragma unroll
    for (int db = 0; db < 8; db++)
      vf[db] = *reinterpret_cast<const bf16x8*>(
          &Vh[(size_t)(db * 16 + lane16) * S_ + k0 + g * 8]);

    f32x4 s01[2][2];
    __builtin_amdgcn_s_setprio(1);
    #pragma unroll
    for (int rf = 0; rf < 2; rf++)
      #pragma unroll
      for (int blk = 0; blk < 2; blk++) {
        f32x4 sa = (f32x4){0.f, 0.f, 0.f, 0.f};
        #pragma unroll
        for (int c = 0; c < 4; c++)
          sa = __builtin_amdgcn_mfma_f32_16x16x32_bf16(qf[rf][c], kf[blk][c], sa, 0, 0, 0);
        s01[rf][blk] = sa;
      }
    __builtin_amdgcn_s_setprio(0);

    // online softmax: row = q0 + rf*16 + g*4 + r, cols = k0 + blk*16 + lane16
    #pragma unroll
    for (int rf = 0; rf < 2; rf++)
      #pragma unroll
      for (int r = 0; r < 4; r++) {
        int i = q0 + rf * 16 + g * 4 + r;
        int j0 = k0 + lane16;
        int j1 = j0 + 16;
        bool v0 = (j0 <= i) && (i - j0 <= WINDOW_);
        bool v1 = (j1 <= i) && (i - j1 <= WINDOW_);
        float sv0 = v0 ? s01[rf][0][r] : -1e30f;
        float sv1 = v1 ? s01[rf][1][r] : -1e30f;
        float a = fmaxf(sv0, sv1);
        #pragma unroll
        for (int d = 8; d >= 1; d >>= 1) a = fmaxf(a, __shfl_xor(a, d));
        float nm = fmaxf(m[rf][r], a);
        float p0 = v0 ? __expf(sv0 - nm) : 0.0f;
        float p1 = v1 ? __expf(sv1 - nm) : 0.0f;
        float rs = p0 + p1;
        #pragma unroll
        for (int d = 8; d >= 1; d >>= 1) rs += __shfl_xor(rs, d);
        float corr = __expf(m[rf][r] - nm);
        l[rf][r] = l[rf][r] * corr + rs;
        m[rf][r] = nm;
        #pragma unroll
        for (int db = 0; db < 8; db++) o[rf][db][r] *= corr;
        Pw[(rf * 16 + g * 4 + r) * PSTR_ + lane16] = f2bf(p0);
        Pw[(rf * 16 + g * 4 + r) * PSTR_ + 16 + lane16] = f2bf(p1);
      }

    bf16x8 pa[2];
    #pragma unroll
    for (int rf = 0; rf < 2; rf++)
      pa[rf] = *reinterpret_cast<const bf16x8*>(&Pw[(rf * 16 + lane16) * PSTR_ + g * 8]);
    __builtin_amdgcn_s_setprio(1);
    #pragma unroll
    for (int rf = 0; rf < 2; rf++)
      #pragma unroll
      for (int db = 0; db < 8; db++)
        o[rf][db] = __builtin_amdgcn_mfma_f32_16x16x32_bf16(pa[rf], vf[db], o[rf][db], 0, 0, 0);
    __builtin_amdgcn_s_setprio(0);
  }

  #pragma unroll
  for (int rf = 0; rf < 2; rf++)
    #pragma unroll
    for (int db = 0; db < 8; db++) {
      #pragma unroll
      for (int r = 0; r < 4; r++) {
        int t = b * S_ + q0 + rf * 16 + g * 4 + r;
        int col = h * HD_ + db * 16 + lane16;
        Oa[(size_t)t * (NH_ * HD_) + col] = f2bf(o[rf][db][r] / l[rf][r]);
      }
    }
}

// ---------------- launch ----------------
extern "C" void kernel_launch(void* const* d_in, const int* in_sizes, int n_in,
                              void* d_out, int out_size, void* d_ws, size_t ws_size,
                              hipStream_t stream) {
  const float* hidden = (const float*)d_in[0];
  const float* cosb  = (const float*)d_in[1];
  const float* sinb  = (const float*)d_in[2];
  const float* qkv_w = (const float*)d_in[3];
  const float* qkv_b = (const float*)d_in[4];
  const float* o_w   = (const float*)d_in[5];
  float* out = (float*)d_out;

  char* ws = (char*)d_ws;
  u16*   hid_bf = (u16*)(ws);                      // 14,680,064 B
  u16*   w_bf   = (u16*)(ws + 14680064);           // 33,030,144 B (qkv_w, later o_w)
  float* qkvf   = (float*)(ws + 47710208);         // 37,748,736 B
  u16*   Qb     = (u16*)(ws + 85458944);           // 14,680,064 B
  u16*   Kb     = (u16*)(ws + 100139008);          //  2,097,152 B
  u16*   Vtb    = (u16*)(ws + 102236160);          //  2,097,152 B
  u16*   attn   = (u16*)(ws + 104333312);          // 14,680,064 B

  cast2_f32_to_bf16<<<2048, 256, 0, stream>>>(
      (const float4*)hidden, (ushort4*)hid_bf, 7340032 / 4,
      (const float4*)qkv_w, (ushort4*)w_bf, 16515072 / 4);

  gemm_bf16_nt<true><<<16 * 36, 256, 0, stream>>>(hid_bf, w_bf, qkv_b, qkvf, T_, QKVD_, H_);

  rope_split_kernel<<<dim3(T_, 8), 256, 0, stream>>>(qkvf, cosb, sinb, Qb, Kb);
  vtrans_kernel<<<dim3(S_ / 64, NKV_, B_), 128, 0, stream>>>(qkvf, Vtb);

  attn_kernel<<<NCAST_ + NH_ * 16 * B_, 128, 0, stream>>>(
      Qb, Kb, Vtb, attn,
      (const float4*)o_w, (ushort4*)w_bf, 12845056 / 4);

  gemm_bf16_nt<false><<<16 * 28, 256, 0, stream>>>(attn, w_bf, nullptr, out, T_, H_, H_);
}